// Round 6
// baseline (459.192 us; speedup 1.0000x reference)
//
#include <hip/hip_runtime.h>

// Fixed problem sizes
#define HID 2048
#define SEQL 4096
#define CHUNK 2048
#define NHEADS 8
#define NKVH 4
#define HDIM 256

typedef __bf16 bf16x4 __attribute__((ext_vector_type(4)));
typedef __bf16 bf16x8 __attribute__((ext_vector_type(8)));
typedef float f32x4 __attribute__((ext_vector_type(4)));
typedef _Float16 f16x4 __attribute__((ext_vector_type(4)));
typedef __attribute__((address_space(1))) unsigned int* as1_u32;
typedef __attribute__((address_space(3))) unsigned int* as3_u32;

// async global->LDS, 16B per lane; LDS dest = wave-uniform base + lane*16
__device__ __forceinline__ void load_lds16(const __bf16* g, __bf16* l) {
  __builtin_amdgcn_global_load_lds((as1_u32)g, (as3_u32)l, 16, 0, 0);
}

// ---------- fused prep: fp32->bf16 convert of X + all 4 weight transposes ----------
// R6: one launch (was cvt_bf16_kernel + transpose_all_kernel) -- saves a launch gap.
// blocks [0,8192): cvt 4 f32->bf16 per thread. blocks [8192,11264): 64x64 transpose
// tiles, vectorized global access (float4 read / bf16x8 write) via scalar-LDS [64][65].
__global__ void prep_kernel(const float* __restrict__ X, __bf16* __restrict__ Y,
                            const float* __restrict__ wq, const float* __restrict__ wk,
                            const float* __restrict__ wv, const float* __restrict__ wo,
                            __bf16* __restrict__ WQT, __bf16* __restrict__ WKVT,
                            __bf16* __restrict__ WOT) {
  if (blockIdx.x < 8192) {
    int i = blockIdx.x * blockDim.x + threadIdx.x;
    const float4* xv = (const float4*)X;
    float4 v = xv[i];
    bf16x4 o;
    o[0] = (__bf16)v.x; o[1] = (__bf16)v.y; o[2] = (__bf16)v.z; o[3] = (__bf16)v.w;
    *(bf16x4*)(Y + i * 4) = o;
    return;
  }
  __shared__ float tile[64][65];
  const int b = blockIdx.x - 8192;
  const float* W;
  __bf16* WT;
  int R, C, bx, by;
  if (b < 1024) { W = wq; WT = WQT; R = 2048; C = 2048; bx = b & 31; by = b >> 5; }
  else if (b < 1536) { int q = b - 1024; W = wk; WT = WKVT; R = 2048; C = 1024; bx = q & 15; by = q >> 4; }
  else if (b < 2048) { int q = b - 1536; W = wv; WT = WKVT + (size_t)1024 * 2048; R = 2048; C = 1024; bx = q & 15; by = q >> 4; }
  else { int q = b - 2048; W = wo; WT = WOT; R = 2048; C = 2048; bx = q & 31; by = q >> 5; }
  int r0 = by * 64, c0 = bx * 64;
#pragma unroll
  for (int it = 0; it < 4; it++) {
    int idx = it * 256 + threadIdx.x;           // 1024 float4 = 64x64 f32
    int r = idx >> 4, c4 = (idx & 15) * 4;
    float4 v = *(const float4*)&W[(size_t)(r0 + r) * C + c0 + c4];
    tile[r][c4] = v.x; tile[r][c4 + 1] = v.y; tile[r][c4 + 2] = v.z; tile[r][c4 + 3] = v.w;
  }
  __syncthreads();
#pragma unroll
  for (int it = 0; it < 2; it++) {
    int idx = it * 256 + threadIdx.x;           // 512 bf16x8 = 64x64 bf16
    int cc = idx >> 3, rb = (idx & 7) * 8;
    bf16x8 o;
#pragma unroll
    for (int j = 0; j < 8; j++) o[j] = (__bf16)tile[rb + j][cc];
    *(bf16x8*)&WT[(size_t)(c0 + cc) * R + r0 + rb] = o;
  }
}

// ---------- 256x256-tile GEMM, 8 waves (2M x 4N), BK=64, counted-vmcnt pipeline ----------
// R5: 2 barriers per K-tile; straight-line {24 ds_read_b128 + 64 MFMA} region lets the
// compiler interleave LDS and MFMA pipes. Counted vmcnt(8): next K-tile's stage stays in
// flight across the barrier, never drained to 0 in the loop. LDS XOR-swizzle
// slot^=(row&7) via pre-swizzled GLOBAL source + swizzled ds_read (rule #21 both-sides).
// Per-acc K-accumulation order identical to R2 kernels (bit-identical fp32 results).
template <int MODE>
__global__ __launch_bounds__(512, 2) void gemm256_kernel(
    const __bf16* __restrict__ A0, const __bf16* __restrict__ B0,
    const __bf16* __restrict__ B1, void* __restrict__ C0, void* __restrict__ C1) {
  __shared__ __bf16 Asm[2][256 * 64];  // 64 KB
  __shared__ __bf16 Bsm[2][256 * 64];  // 64 KB
  const int tid = threadIdx.x;
  const int lane = tid & 63, wave = tid >> 6;
  const int quad = lane >> 4, l15 = lane & 15;
  const int wm = (wave & 1) * 128, wn = (wave >> 1) * 64;

  const __bf16 *A, *B;
  char* Cb;
  int m0, n0;
  if (MODE == 0) {
    int b = blockIdx.x;
    if (b < 128) { A = A0; B = B0; Cb = (char*)C0; m0 = (b & 15) * 256; n0 = (b >> 4) * 256; }
    else { int q = b - 128; A = A0 + (size_t)2048 * 2048; B = B1; Cb = (char*)C1; m0 = (q & 7) * 256; n0 = (q >> 3) * 256; }
  } else {
    A = A0; B = B0; Cb = (char*)C0;
    m0 = (int)(blockIdx.x & 7) * 256; n0 = (int)(blockIdx.x >> 3) * 256;
  }

  f32x4 acc[8][4];
#pragma unroll
  for (int i = 0; i < 8; i++)
#pragma unroll
    for (int j = 0; j < 4; j++) acc[i][j] = (f32x4){0.f, 0.f, 0.f, 0.f};

  const int rr = tid >> 3;
  const int gch = (tid & 7) ^ ((tid >> 3) & 7);
  const int ldsb = wave * 512;  // wave-uniform LDS elem base within each 64-row group

  const int sx = l15 & 7;
  const int s0 = ((0 + quad) ^ sx) * 8;
  const int s1 = ((4 + quad) ^ sx) * 8;

#define STAGE(T, BF)                                                                  \
  {                                                                                   \
    const int k0s = (T) * 64;                                                         \
    _Pragma("unroll")                                                                 \
    for (int a = 0; a < 4; a++) {                                                     \
      load_lds16(A + (size_t)(m0 + a * 64 + rr) * 2048 + k0s + gch * 8,               \
                 &Asm[BF][a * 4096 + ldsb]);                                          \
      load_lds16(B + (size_t)(n0 + a * 64 + rr) * 2048 + k0s + gch * 8,               \
                 &Bsm[BF][a * 4096 + ldsb]);                                          \
    }                                                                                 \
  }

#define LDA(MH, BF)                                                                   \
  _Pragma("unroll")                                                                   \
  for (int mi = 0; mi < 4; mi++) {                                                    \
    const int rowb = (wm + (MH) * 64 + mi * 16 + l15) * 64;                           \
    af[mi * 2 + 0] = *(const bf16x8*)(&Asm[BF][rowb + s0]);                           \
    af[mi * 2 + 1] = *(const bf16x8*)(&Asm[BF][rowb + s1]);                           \
  }

#define LDB(DST, NH, BF)                                                              \
  _Pragma("unroll")                                                                   \
  for (int ni = 0; ni < 2; ni++) {                                                    \
    const int rowb = (wn + (NH) * 32 + ni * 16 + l15) * 64;                           \
    DST[ni * 2 + 0] = *(const bf16x8*)(&Bsm[BF][rowb + s0]);                          \
    DST[ni * 2 + 1] = *(const bf16x8*)(&Bsm[BF][rowb + s1]);                          \
  }

#define MMA(MH, NH, BV)                                                               \
  _Pragma("unroll")                                                                   \
  for (int mi = 0; mi < 4; mi++)                                                      \
    _Pragma("unroll")                                                                 \
    for (int ni = 0; ni < 2; ni++) {                                                  \
      acc[(MH) * 4 + mi][(NH) * 2 + ni] = __builtin_amdgcn_mfma_f32_16x16x32_bf16(    \
          af[mi * 2 + 0], BV[ni * 2 + 0], acc[(MH) * 4 + mi][(NH) * 2 + ni], 0, 0, 0);\
      acc[(MH) * 4 + mi][(NH) * 2 + ni] = __builtin_amdgcn_mfma_f32_16x16x32_bf16(    \
          af[mi * 2 + 1], BV[ni * 2 + 1], acc[(MH) * 4 + mi][(NH) * 2 + ni], 0, 0, 0);\
    }

  bf16x8 af[8], bX[4], bY[4];

  STAGE(0, 0);
  STAGE(1, 1);
  asm volatile("s_waitcnt vmcnt(8)" ::: "memory");  // tile0 landed; tile1 in flight
  __builtin_amdgcn_s_barrier();

  const int NT = 32;  // K = 2048 / BK = 64
#pragma unroll 2
  for (int t = 0; t < NT; t++) {
    const int c = t & 1;
    LDA(0, c);
    LDB(bX, 0, c);
    LDB(bY, 1, c);
    MMA(0, 0, bX);
    MMA(0, 1, bY);
    LDA(1, c);
    MMA(1, 1, bY);
    MMA(1, 0, bX);
    __builtin_amdgcn_s_barrier();  // all waves done reading buf c -> safe to restage it
    if (t + 2 < NT) {
      STAGE(t + 2, c);
      asm volatile("s_waitcnt vmcnt(8)" ::: "memory");  // t+1 complete; t+2 in flight
      __builtin_amdgcn_s_barrier();
    } else if (t + 1 < NT) {
      asm volatile("s_waitcnt vmcnt(0)" ::: "memory");  // tail: drain last tile
      __builtin_amdgcn_s_barrier();
    }
  }

#pragma unroll
  for (int mh = 0; mh < 2; mh++)
#pragma unroll
    for (int mi = 0; mi < 4; mi++) {
      const int r = m0 + wm + mh * 64 + mi * 16 + quad * 4;
#pragma unroll
      for (int ni = 0; ni < 4; ni++) {
        const int cc = n0 + wn + (ni >> 1) * 32 + (ni & 1) * 16 + l15;
#pragma unroll
        for (int j = 0; j < 4; j++) {
          if (MODE == 1)
            ((float*)Cb)[(size_t)(r + j) * 2048 + cc] = acc[mh * 4 + mi][ni][j];
          else
            ((__bf16*)Cb)[(size_t)(r + j) * 2048 + cc] = (__bf16)acc[mh * 4 + mi][ni][j];
        }
      }
    }
#undef STAGE
#undef LDA
#undef LDB
#undef MMA
}

// ---------- C(MxN) = A(MxK) @ B^T(NxK), bf16 in, fp32 acc (output projection) ----------
// R2-proven structure; NI=4 -> 128x128 tiles (256 blocks, all-resident).
template <int NI, bool F32OUT>
__global__ __launch_bounds__(256, 2) void gemm_bt_kernel(
    const __bf16* __restrict__ A, const __bf16* __restrict__ B,
    void* __restrict__ Cv, int M, int N, int Kd) {
  constexpr int BN = NI * 32;
  __shared__ __bf16 Asm[2][128 * 32];
  __shared__ __bf16 Bsm[2][BN * 32];
  const int tid = threadIdx.x;
  const int lane = tid & 63, wave = tid >> 6;
  const int quad = lane >> 4, l15 = lane & 15;
  const int m0 = blockIdx.x * 128, n0 = blockIdx.y * BN;
  const int wm = (wave & 1) * 64, wn = (wave >> 1) * (NI * 16);
  f32x4 acc[4][NI];
#pragma unroll
  for (int i = 0; i < 4; i++)
#pragma unroll
    for (int j = 0; j < NI; j++) acc[i][j] = (f32x4){0.f, 0.f, 0.f, 0.f};

  const int rA = lane >> 2, cA = (lane & 3) * 8;

  // prologue: stage k0=0 into buf 0
#pragma unroll
  for (int c = wave; c < 8; c += 4)
    load_lds16(A + (size_t)(m0 + c * 16 + rA) * Kd + cA, &Asm[0][c * 512]);
#pragma unroll
  for (int c = wave; c < BN / 16; c += 4)
    load_lds16(B + (size_t)(n0 + c * 16 + rA) * Kd + cA, &Bsm[0][c * 512]);

  for (int k0 = 0; k0 < Kd; k0 += 32) {
    const int buf = (k0 >> 5) & 1;
    __syncthreads();
    if (k0 + 32 < Kd) {
#pragma unroll
      for (int c = wave; c < 8; c += 4)
        load_lds16(A + (size_t)(m0 + c * 16 + rA) * Kd + k0 + 32 + cA, &Asm[buf ^ 1][c * 512]);
#pragma unroll
      for (int c = wave; c < BN / 16; c += 4)
        load_lds16(B + (size_t)(n0 + c * 16 + rA) * Kd + k0 + 32 + cA, &Bsm[buf ^ 1][c * 512]);
    }
    bf16x8 af[4], bfr[NI];
#pragma unroll
    for (int i = 0; i < 4; i++)
      af[i] = *(const bf16x8*)(&Asm[buf][(wm + i * 16 + l15) * 32 + quad * 8]);
#pragma unroll
    for (int i = 0; i < NI; i++)
      bfr[i] = *(const bf16x8*)(&Bsm[buf][(wn + i * 16 + l15) * 32 + quad * 8]);
#pragma unroll
    for (int mi = 0; mi < 4; mi++)
#pragma unroll
      for (int ni = 0; ni < NI; ni++)
        acc[mi][ni] = __builtin_amdgcn_mfma_f32_16x16x32_bf16(af[mi], bfr[ni], acc[mi][ni], 0, 0, 0);
  }
#pragma unroll
  for (int mi = 0; mi < 4; mi++) {
    int r = m0 + wm + mi * 16 + quad * 4;
#pragma unroll
    for (int ni = 0; ni < NI; ni++) {
      int cc = n0 + wn + ni * 16 + l15;
#pragma unroll
      for (int j = 0; j < 4; j++) {
        if (F32OUT)
          ((float*)Cv)[(size_t)(r + j) * N + cc] = acc[mi][ni][j];
        else
          ((__bf16*)Cv)[(size_t)(r + j) * N + cc] = (__bf16)acc[mi][ni][j];
      }
    }
  }
}

// ---------- unified RMSNorm (+RoPE) for Q, K, V in one launch ----------
// R3: V branch writes normalized V back to KVp (coalesced); VT produced by vtrans_kernel.
__global__ void norm_all_kernel(__bf16* __restrict__ Qp, __bf16* __restrict__ KVp,
                                const float* __restrict__ cosb, const float* __restrict__ sinb,
                                const float* __restrict__ qw, const float* __restrict__ kw,
                                const float* __restrict__ vw) {
  const int gw = (blockIdx.x * 256 + threadIdx.x) >> 6;
  const int lane = threadIdx.x & 63;
  const int d0 = lane * 4;

  __bf16* row;
  const float* w;
  int pos = -1;
  bool isV = false;
  float prescale = 1.f;
  if (gw < 16384) {
    int t = gw >> 3, h = gw & 7;
    row = Qp + (size_t)t * 2048 + h * 256;
    w = qw; pos = t + 2048; prescale = 0.0625f;
  } else {
    int g2 = gw - 16384;
    int t = g2 >> 3, r = g2 & 7;
    if (r < 4) {
      row = KVp + (size_t)t * 2048 + r * 256;
      w = kw; pos = t;
    } else {
      row = KVp + (size_t)t * 2048 + 1024 + (r - 4) * 256;
      w = vw; isV = true;
    }
  }

  bf16x4 rv = *(const bf16x4*)(row + d0);
  float x[4];
  float ss = 0.f;
#pragma unroll
  for (int j = 0; j < 4; j++) { x[j] = (float)rv[j]; ss += x[j] * x[j]; }
#pragma unroll
  for (int off = 1; off < 64; off <<= 1) ss += __shfl_xor(ss, off);
  float scale = rsqrtf(ss * (1.f / 256.f) + 1e-6f);
  float n[4];
#pragma unroll
  for (int j = 0; j < 4; j++) n[j] = x[j] * scale * (1.f + w[d0 + j]);

  if (!isV) {
    const float* cp = cosb + (size_t)pos * 256 + d0;
    const float* sp = sinb + (size_t)pos * 256 + d0;
    bf16x4 ov;
#pragma unroll
    for (int j = 0; j < 4; j++) {
      float other = __shfl_xor(n[j], 32);           // d and d^128 live in lane^32
      float rot = (lane < 32) ? -other : other;     // rotate_half sign
      ov[j] = (__bf16)((n[j] * cp[j] + rot * sp[j]) * prescale);
    }
    *(bf16x4*)(row + d0) = ov;
  } else {
    bf16x4 ov;
#pragma unroll
    for (int j = 0; j < 4; j++) ov[j] = (__bf16)n[j];
    *(bf16x4*)(row + d0) = ov;
  }
}

// ---------- V transpose: KVp[t][1024 + h*256 + d] -> VT[h][d][t], 64x64 LDS tiles ----------
// R4: pad 72 (144B rows) keeps all bf16x8 LDS accesses 16B-aligned.
__global__ void vtrans_kernel(const __bf16* __restrict__ KVp, __bf16* __restrict__ VT) {
  __shared__ __bf16 tile[64][72];
  const int b = blockIdx.x;        // 1024 = 4 heads * 64 t-tiles * 4 d-tiles
  const int h = b >> 8;
  const int r = b & 255;
  const int t0 = (r >> 2) * 64;
  const int d0 = (r & 3) * 64;
  const __bf16* src = KVp + 1024 + h * 256 + d0;
#pragma unroll
  for (int it = 0; it < 2; it++) {
    int idx = it * 256 + threadIdx.x;
    int tt = idx >> 3, dd = (idx & 7) * 8;
    *(bf16x8*)(&tile[tt][dd]) = *(const bf16x8*)(src + (size_t)(t0 + tt) * 2048 + dd);
  }
  __syncthreads();
  __bf16* dst = VT + (size_t)h * (256 * 4096) + (size_t)d0 * 4096 + t0;
#pragma unroll
  for (int it = 0; it < 2; it++) {
    int idx = it * 256 + threadIdx.x;
    int dd = idx >> 3, tt = (idx & 7) * 8;
    bf16x8 o;
#pragma unroll
    for (int j = 0; j < 8; j++) o[j] = tile[tt + j][dd];
    *(bf16x8*)(dst + (size_t)dd * 4096 + tt) = o;
  }
}

// ---------- flash attention, fixed softmax max (softcap bounds logits to +-50) ----------
// 512 blocks; (b, b+256) co-reside on a CU -> qt remap pairs long+short tiles (49 steps/CU).
// KV-split x4 is INTERLEAVED: sp processes steps s = 4i+sp (t0=(4i+sp)*32), so all
// resident blocks on an XCD walk the same ~128-key window together -> K/V stays L2-hot.
// Causal mask: each sp's LAST step is its diagonal step (s=T-4+sp).
// R1: K LDS tile XOR-swizzled (conflicts 6.8M -> 0.4M). R2: no setprio (lockstep waves).
// R6: V read DIRECTLY from global (VT, L2-hot by the interleaved-window design) at the
//     PV use site -- drops Vsm (32 KB LDS), 16 staging loads/block/step, and 16
//     ds_read_b128/wave/step off the LDS pipe (Common-mistake #7 / m169 precedent).
//     V values and MFMA order unchanged -> bit-identical output.
__global__ __launch_bounds__(256, 2) void attn_kernel(
    const __bf16* __restrict__ Q,   // [2048][8*256] post norm+rope, prescaled 2^-4
    const __bf16* __restrict__ K,   // [4096][2048] cols 0..1023 = K heads (post norm+rope)
    const __bf16* __restrict__ VT,  // [4][256][4096] post norm, transposed
    _Float16* __restrict__ Op,      // [4][2048][2048] normalized partial O (fp16)
    float* __restrict__ Lp) {       // [4][2048][8]    partial l (fp32)
  __shared__ __bf16 Ksm[2][8][32][32];  // 32 KB  [buf][d-panel][key][d]   (swizzled)
  __shared__ __bf16 Pex[4][32][40];     // 10 KB  per-wave P C->A exchange
  const int tid = threadIdx.x;
  const int lane = tid & 63, wave = tid >> 6;
  const int quad = lane >> 4, l15 = lane & 15;
  const int b = blockIdx.x;
  const int idx = b & 255;
  const int h = idx & 7, sp = (idx >> 3) & 3;
  int qt = idx >> 5;                    // 0..7
  if (b >= 256) qt = 15 - qt;           // long-short pairing on co-resident CUs
  const int kvh = h >> 1;

  const int T = 68 + 4 * qt;            // total 32-key steps; T % 4 == 0 always
  const int nst = T >> 2;               // this split handles s = sp, sp+4, ..., T-4+sp

  bf16x8 qf[2][8];
#pragma unroll
  for (int r = 0; r < 2; r++) {
    const __bf16* qp = Q + (size_t)(qt * 128 + wave * 32 + r * 16 + l15) * 2048 + h * 256 + quad * 8;
#pragma unroll
    for (int s = 0; s < 8; s++) qf[r][s] = *(const bf16x8*)(qp + s * 32);
  }
  f32x4 o[2][16];
#pragma unroll
  for (int r = 0; r < 2; r++)
#pragma unroll
    for (int i = 0; i < 16; i++) o[r][i] = (f32x4){0.f, 0.f, 0.f, 0.f};
  float rs[2][4] = {{0.f, 0.f, 0.f, 0.f}, {0.f, 0.f, 0.f, 0.f}};

  const __bf16* Kb = K + kvh * 256;
  const __bf16* Vb = VT + (size_t)kvh * (256 * 4096);
  const int rA = lane >> 2;
  // swizzled source column: LDS slot (lane&3) of row rA gets global slot (lane&3)^((rA>>1)&3)
  const int cAs = (((lane & 3) ^ ((rA >> 1) & 3)) * 8);
  // swizzled read column
  const int kx = (quad ^ ((l15 >> 1) & 3)) * 8;
  const int qbase = 2048 + qt * 128 + wave * 32 + quad * 4;  // + r*16 + j

  // stage step s=sp into buf 0 (K only; V is read direct-from-global in PV)
  {
    const int t0 = sp * 32;
#pragma unroll
    for (int ch = 0; ch < 4; ch++) {
      int cc = wave + ch * 4;
      int s = cc >> 1, hf = cc & 1;
      load_lds16(Kb + (size_t)(t0 + hf * 16 + rA) * 2048 + s * 32 + cAs, &Ksm[0][s][hf * 16][0]);
    }
  }

  for (int i = 0; i < nst; i++) {
    const int buf = i & 1;
    const int t0 = (4 * i + sp) * 32;
    __syncthreads();  // buf ready; all waves done with other buf
    if (i + 1 < nst) {
      const int t1 = t0 + 128;
#pragma unroll
      for (int ch = 0; ch < 4; ch++) {
        int cc = wave + ch * 4;
        int s = cc >> 1, hf = cc & 1;
        load_lds16(Kb + (size_t)(t1 + hf * 16 + rA) * 2048 + s * 32 + cAs, &Ksm[buf ^ 1][s][hf * 16][0]);
      }
    }

    // S = Q K^T : 32q x 32k per wave; each K B-frag feeds 2 MFMAs (r=0,1)
    f32x4 s4[2][2];
    s4[0][0] = (f32x4){0.f, 0.f, 0.f, 0.f};
    s4[0][1] = s4[0][0]; s4[1][0] = s4[0][0]; s4[1][1] = s4[0][0];
#pragma unroll
    for (int s = 0; s < 8; s++) {
      bf16x8 b0 = *(const bf16x8*)(&Ksm[buf][s][l15][kx]);
      bf16x8 b1 = *(const bf16x8*)(&Ksm[buf][s][16 + l15][kx]);
      s4[0][0] = __builtin_amdgcn_mfma_f32_16x16x32_bf16(qf[0][s], b0, s4[0][0], 0, 0, 0);
      s4[0][1] = __builtin_amdgcn_mfma_f32_16x16x32_bf16(qf[0][s], b1, s4[0][1], 0, 0, 0);
      s4[1][0] = __builtin_amdgcn_mfma_f32_16x16x32_bf16(qf[1][s], b0, s4[1][0], 0, 0, 0);
      s4[1][1] = __builtin_amdgcn_mfma_f32_16x16x32_bf16(qf[1][s], b1, s4[1][1], 0, 0, 0);
    }

    // p = exp(50*tanh(v/50) - 50) = exp(-100/(e^{0.04v}+1)); max pinned at 50.
    const bool mk = (i == nst - 1);     // diagonal step for this sp
#pragma unroll
    for (int r = 0; r < 2; r++)
#pragma unroll
      for (int nt = 0; nt < 2; nt++) {
        const int key = t0 + nt * 16 + l15;
#pragma unroll
        for (int j = 0; j < 4; j++) {
          float v = s4[r][nt][j];
          float e = __expf(v * 0.04f);
          float p = __expf(-100.f * __builtin_amdgcn_rcpf(e + 1.f));
          if (mk && key > qbase + r * 16 + j) p = 0.f;
          s4[r][nt][j] = p;
          rs[r][j] += p;  // per-lane partial; cross-lane reduce at end
        }
      }

    // P: C-layout -> LDS -> A-layout (per-wave slab)
#pragma unroll
    for (int r = 0; r < 2; r++)
#pragma unroll
      for (int nt = 0; nt < 2; nt++)
#pragma unroll
        for (int j = 0; j < 4; j++)
          Pex[wave][r * 16 + quad * 4 + j][nt * 16 + l15] = (__bf16)s4[r][nt][j];

    bf16x8 pf0 = *(const bf16x8*)(&Pex[wave][l15][quad * 8]);
    bf16x8 pf1 = *(const bf16x8*)(&Pex[wave][16 + l15][quad * 8]);
    // PV: V B-frags read straight from global VT (16B contiguous in t; L2-hot window).
    const __bf16* Vp = Vb + t0 + quad * 8;
#pragma unroll
    for (int d = 0; d < 16; d++) {
      bf16x8 vf = *(const bf16x8*)(Vp + (size_t)(d * 16 + l15) * 4096);
      o[0][d] = __builtin_amdgcn_mfma_f32_16x16x32_bf16(pf0, vf, o[0][d], 0, 0, 0);
      o[1][d] = __builtin_amdgcn_mfma_f32_16x16x32_bf16(pf1, vf, o[1][d], 0, 0, 0);
    }
  }

  // reduce row-sums over the 16 key-columns held across l15 lanes
#pragma unroll
  for (int off = 1; off < 16; off <<= 1)
#pragma unroll
    for (int r = 0; r < 2; r++)
#pragma unroll
      for (int j = 0; j < 4; j++) rs[r][j] += __shfl_xor(rs[r][j], off);

  _Float16* Os = Op + (size_t)sp * (2048 * 2048);
  float* Ls = Lp + sp * (2048 * 8);
#pragma unroll
  for (int r = 0; r < 2; r++) {
    float inv[4];
#pragma unroll
    for (int j = 0; j < 4; j++)
      inv[j] = rs[r][j] > 0.f ? 1.f / rs[r][j] : 0.f;
    const int trow = qt * 128 + wave * 32 + r * 16 + quad * 4;
#pragma unroll
    for (int d = 0; d < 16; d++) {
      const int col = h * 256 + d * 16 + l15;
#pragma unroll
      for (int j = 0; j < 4; j++)
        Os[(size_t)(trow + j) * 2048 + col] = (_Float16)(o[r][d][j] * inv[j]);
    }
    if (l15 == 0) {
#pragma unroll
      for (int j = 0; j < 4; j++) Ls[(trow + j) * 8 + h] = rs[r][j];
    }
  }
}

// ---------- merge: O = sum(l_i * Onorm_i) / sum(l_i) ----------
__global__ void merge_kernel(const _Float16* __restrict__ Op, const float* __restrict__ Lp,
                             __bf16* __restrict__ AO) {
  int f = (blockIdx.x * 256 + threadIdx.x) * 4;
  int q = f >> 11, col = f & 2047, h = col >> 8;
  float lsum = 0.f;
  float acc[4] = {0.f, 0.f, 0.f, 0.f};
#pragma unroll
  for (int s = 0; s < 4; s++) {
    float l = Lp[s * (2048 * 8) + q * 8 + h];
    lsum += l;
    f16x4 v = *(const f16x4*)(Op + (size_t)s * (2048 * 2048) + f);
#pragma unroll
    for (int j = 0; j < 4; j++) acc[j] += l * (float)v[j];
  }
  float inv = 1.f / lsum;
  bf16x4 o;
#pragma unroll
  for (int j = 0; j < 4; j++) o[j] = (__bf16)(acc[j] * inv);
  *(bf16x4*)(AO + f) = o;
}

extern "C" void kernel_launch(void* const* d_in, const int* in_sizes, int n_in,
                              void* d_out, int out_size, void* d_ws, size_t ws_size,
                              hipStream_t stream) {
  const float* hidden = (const float*)d_in[0];
  const float* cosb = (const float*)d_in[1];
  const float* sinb = (const float*)d_in[2];
  // d_in[3] attention_mask: causal, reproduced analytically
  const float* wq = (const float*)d_in[4];
  const float* wk = (const float*)d_in[5];
  const float* wv = (const float*)d_in[6];
  const float* wo = (const float*)d_in[7];
  const float* qw = (const float*)d_in[8];
  const float* kw = (const float*)d_in[9];
  const float* vw = (const float*)d_in[10];
  float* outp = (float*)d_out;

  char* p = (char*)d_ws;
  __bf16* Xb = (__bf16*)p;   p += (size_t)SEQL * HID * 2;       // 16 MB (dead after GEMMs)
  __bf16* WQT = (__bf16*)p;  p += (size_t)2048 * 2048 * 2;      // 8 MB  (dead after Q GEMM)
  __bf16* WKVT = (__bf16*)p; p += (size_t)2048 * 2048 * 2;      // 8 MB  (dead after KV GEMM)
  __bf16* WOT = (__bf16*)p;  p += (size_t)2048 * 2048 * 2;      // 8 MB
  __bf16* Qp = (__bf16*)p;   p += (size_t)2048 * 2048 * 2;      // 8 MB
  __bf16* KVp = (__bf16*)p;  p += (size_t)4096 * 2048 * 2;      // 16 MB
  __bf16* VT = (__bf16*)p;   p += (size_t)4 * 256 * 4096 * 2;   // 8 MB
  __bf16* AO = (__bf16*)p;   p += (size_t)2048 * 2048 * 2;      // 8 MB
  float* Lpart = (float*)p;  p += (size_t)4 * 2048 * 8 * 4;     // 256 KB (total ~80.3 MB)
  // fp16 normalized partial O (4 x 8 MB = 32 MB) overlays the dead
  // Xb(16)+WQT(8)+WKVT(8) regions (contiguous, end exactly at WOT).
  _Float16* Opart = (_Float16*)Xb;

  // 1) fused prep: X convert + all weight transposes (one launch)
  prep_kernel<<<11264, 256, 0, stream>>>(hidden, Xb, wq, wk, wv, wo, WQT, WKVT, WOT);

  // 2) fused Q + KV projections: 192 blocks of 256x256 (128 KV + 64 Q), 512 threads
  gemm256_kernel<0><<<192, 512, 0, stream>>>(Xb, WKVT, WQT, KVp, Qp);

  // 3) unified RMSNorm (+RoPE); V written back coalesced, then tiled transpose -> VT
  norm_all_kernel<<<12288, 256, 0, stream>>>(Qp, KVp, cosb, sinb, qw, kw, vw);
  vtrans_kernel<<<1024, 256, 0, stream>>>(KVp, VT);

  // 4) flash attention, interleaved KV-split x4 (L2-hot), fp16 normalized partials
  attn_kernel<<<512, 256, 0, stream>>>(Qp, KVp, VT, Opart, Lpart);
  merge_kernel<<<4096, 256, 0, stream>>>(Opart, Lpart, AO);

  // 5) output projection -> fp32 (128x128 tiles, 256 blocks, 2/CU)
  gemm_bt_kernel<4, true><<<dim3(16, 16), 256, 0, stream>>>(AO, WOT, outp, 2048, 2048, 2048);
}

// Round 8
// 361.781 us; speedup vs baseline: 1.2693x; 1.2693x over previous
//
#include <hip/hip_runtime.h>

// Fixed problem sizes
#define HID 2048
#define SEQL 4096
#define CHUNK 2048
#define NHEADS 8
#define NKVH 4
#define HDIM 256

typedef __bf16 bf16x4 __attribute__((ext_vector_type(4)));
typedef __bf16 bf16x8 __attribute__((ext_vector_type(8)));
typedef float f32x4 __attribute__((ext_vector_type(4)));
typedef _Float16 f16x4 __attribute__((ext_vector_type(4)));
typedef __attribute__((address_space(1))) unsigned int* as1_u32;
typedef __attribute__((address_space(3))) unsigned int* as3_u32;

// async global->LDS, 16B per lane; LDS dest = wave-uniform base + lane*16
__device__ __forceinline__ void load_lds16(const __bf16* g, __bf16* l) {
  __builtin_amdgcn_global_load_lds((as1_u32)g, (as3_u32)l, 16, 0, 0);
}

// ---------- fused prep: fp32->bf16 convert of X + all 4 weight transposes ----------
// R6: one launch; measured ~neutral vs two launches (kept: fewer gaps).
// R8: byte-identical resubmission of R7 (previously-passing components; container
//     failure attributed to infra flake -- see journal).
__global__ void prep_kernel(const float* __restrict__ X, __bf16* __restrict__ Y,
                            const float* __restrict__ wq, const float* __restrict__ wk,
                            const float* __restrict__ wv, const float* __restrict__ wo,
                            __bf16* __restrict__ WQT, __bf16* __restrict__ WKVT,
                            __bf16* __restrict__ WOT) {
  if (blockIdx.x < 8192) {
    int i = blockIdx.x * blockDim.x + threadIdx.x;
    const float4* xv = (const float4*)X;
    float4 v = xv[i];
    bf16x4 o;
    o[0] = (__bf16)v.x; o[1] = (__bf16)v.y; o[2] = (__bf16)v.z; o[3] = (__bf16)v.w;
    *(bf16x4*)(Y + i * 4) = o;
    return;
  }
  __shared__ float tile[64][65];
  const int b = blockIdx.x - 8192;
  const float* W;
  __bf16* WT;
  int R, C, bx, by;
  if (b < 1024) { W = wq; WT = WQT; R = 2048; C = 2048; bx = b & 31; by = b >> 5; }
  else if (b < 1536) { int q = b - 1024; W = wk; WT = WKVT; R = 2048; C = 1024; bx = q & 15; by = q >> 4; }
  else if (b < 2048) { int q = b - 1536; W = wv; WT = WKVT + (size_t)1024 * 2048; R = 2048; C = 1024; bx = q & 15; by = q >> 4; }
  else { int q = b - 2048; W = wo; WT = WOT; R = 2048; C = 2048; bx = q & 31; by = q >> 5; }
  int r0 = by * 64, c0 = bx * 64;
#pragma unroll
  for (int it = 0; it < 4; it++) {
    int idx = it * 256 + threadIdx.x;           // 1024 float4 = 64x64 f32
    int r = idx >> 4, c4 = (idx & 15) * 4;
    float4 v = *(const float4*)&W[(size_t)(r0 + r) * C + c0 + c4];
    tile[r][c4] = v.x; tile[r][c4 + 1] = v.y; tile[r][c4 + 2] = v.z; tile[r][c4 + 3] = v.w;
  }
  __syncthreads();
#pragma unroll
  for (int it = 0; it < 2; it++) {
    int idx = it * 256 + threadIdx.x;           // 512 bf16x8 = 64x64 bf16
    int cc = idx >> 3, rb = (idx & 7) * 8;
    bf16x8 o;
#pragma unroll
    for (int j = 0; j < 8; j++) o[j] = (__bf16)tile[rb + j][cc];
    *(bf16x8*)&WT[(size_t)(c0 + cc) * R + r0 + rb] = o;
  }
}

// ---------- 256x256-tile GEMM, 8 waves (2M x 4N), BK=64, counted-vmcnt pipeline ----------
// R5: 2 barriers per K-tile; straight-line {24 ds_read_b128 + 64 MFMA} region lets the
// compiler interleave LDS and MFMA pipes. Counted vmcnt(8): next K-tile's stage stays in
// flight across the barrier, never drained to 0 in the loop. LDS XOR-swizzle
// slot^=(row&7) via pre-swizzled GLOBAL source + swizzled ds_read (rule #21 both-sides).
template <int MODE>
__global__ __launch_bounds__(512, 2) void gemm256_kernel(
    const __bf16* __restrict__ A0, const __bf16* __restrict__ B0,
    const __bf16* __restrict__ B1, void* __restrict__ C0, void* __restrict__ C1) {
  __shared__ __bf16 Asm[2][256 * 64];  // 64 KB
  __shared__ __bf16 Bsm[2][256 * 64];  // 64 KB
  const int tid = threadIdx.x;
  const int lane = tid & 63, wave = tid >> 6;
  const int quad = lane >> 4, l15 = lane & 15;
  const int wm = (wave & 1) * 128, wn = (wave >> 1) * 64;

  const __bf16 *A, *B;
  char* Cb;
  int m0, n0;
  if (MODE == 0) {
    int b = blockIdx.x;
    if (b < 128) { A = A0; B = B0; Cb = (char*)C0; m0 = (b & 15) * 256; n0 = (b >> 4) * 256; }
    else { int q = b - 128; A = A0 + (size_t)2048 * 2048; B = B1; Cb = (char*)C1; m0 = (q & 7) * 256; n0 = (q >> 3) * 256; }
  } else {
    A = A0; B = B0; Cb = (char*)C0;
    m0 = (int)(blockIdx.x & 7) * 256; n0 = (int)(blockIdx.x >> 3) * 256;
  }

  f32x4 acc[8][4];
#pragma unroll
  for (int i = 0; i < 8; i++)
#pragma unroll
    for (int j = 0; j < 4; j++) acc[i][j] = (f32x4){0.f, 0.f, 0.f, 0.f};

  const int rr = tid >> 3;
  const int gch = (tid & 7) ^ ((tid >> 3) & 7);
  const int ldsb = wave * 512;  // wave-uniform LDS elem base within each 64-row group

  const int sx = l15 & 7;
  const int s0 = ((0 + quad) ^ sx) * 8;
  const int s1 = ((4 + quad) ^ sx) * 8;

#define STAGE(T, BF)                                                                  \
  {                                                                                   \
    const int k0s = (T) * 64;                                                         \
    _Pragma("unroll")                                                                 \
    for (int a = 0; a < 4; a++) {                                                     \
      load_lds16(A + (size_t)(m0 + a * 64 + rr) * 2048 + k0s + gch * 8,               \
                 &Asm[BF][a * 4096 + ldsb]);                                          \
      load_lds16(B + (size_t)(n0 + a * 64 + rr) * 2048 + k0s + gch * 8,               \
                 &Bsm[BF][a * 4096 + ldsb]);                                          \
    }                                                                                 \
  }

#define LDA(MH, BF)                                                                   \
  _Pragma("unroll")                                                                   \
  for (int mi = 0; mi < 4; mi++) {                                                    \
    const int rowb = (wm + (MH) * 64 + mi * 16 + l15) * 64;                           \
    af[mi * 2 + 0] = *(const bf16x8*)(&Asm[BF][rowb + s0]);                           \
    af[mi * 2 + 1] = *(const bf16x8*)(&Asm[BF][rowb + s1]);                           \
  }

#define LDB(DST, NH, BF)                                                              \
  _Pragma("unroll")                                                                   \
  for (int ni = 0; ni < 2; ni++) {                                                    \
    const int rowb = (wn + (NH) * 32 + ni * 16 + l15) * 64;                           \
    DST[ni * 2 + 0] = *(const bf16x8*)(&Bsm[BF][rowb + s0]);                          \
    DST[ni * 2 + 1] = *(const bf16x8*)(&Bsm[BF][rowb + s1]);                          \
  }

#define MMA(MH, NH, BV)                                                               \
  _Pragma("unroll")                                                                   \
  for (int mi = 0; mi < 4; mi++)                                                      \
    _Pragma("unroll")                                                                 \
    for (int ni = 0; ni < 2; ni++) {                                                  \
      acc[(MH) * 4 + mi][(NH) * 2 + ni] = __builtin_amdgcn_mfma_f32_16x16x32_bf16(    \
          af[mi * 2 + 0], BV[ni * 2 + 0], acc[(MH) * 4 + mi][(NH) * 2 + ni], 0, 0, 0);\
      acc[(MH) * 4 + mi][(NH) * 2 + ni] = __builtin_amdgcn_mfma_f32_16x16x32_bf16(    \
          af[mi * 2 + 1], BV[ni * 2 + 1], acc[(MH) * 4 + mi][(NH) * 2 + ni], 0, 0, 0);\
    }

  bf16x8 af[8], bX[4], bY[4];

  STAGE(0, 0);
  STAGE(1, 1);
  asm volatile("s_waitcnt vmcnt(8)" ::: "memory");  // tile0 landed; tile1 in flight
  __builtin_amdgcn_s_barrier();

  const int NT = 32;  // K = 2048 / BK = 64
#pragma unroll 2
  for (int t = 0; t < NT; t++) {
    const int c = t & 1;
    LDA(0, c);
    LDB(bX, 0, c);
    LDB(bY, 1, c);
    MMA(0, 0, bX);
    MMA(0, 1, bY);
    LDA(1, c);
    MMA(1, 1, bY);
    MMA(1, 0, bX);
    __builtin_amdgcn_s_barrier();  // all waves done reading buf c -> safe to restage it
    if (t + 2 < NT) {
      STAGE(t + 2, c);
      asm volatile("s_waitcnt vmcnt(8)" ::: "memory");  // t+1 complete; t+2 in flight
      __builtin_amdgcn_s_barrier();
    } else if (t + 1 < NT) {
      asm volatile("s_waitcnt vmcnt(0)" ::: "memory");  // tail: drain last tile
      __builtin_amdgcn_s_barrier();
    }
  }

#pragma unroll
  for (int mh = 0; mh < 2; mh++)
#pragma unroll
    for (int mi = 0; mi < 4; mi++) {
      const int r = m0 + wm + mh * 64 + mi * 16 + quad * 4;
#pragma unroll
      for (int ni = 0; ni < 4; ni++) {
        const int cc = n0 + wn + (ni >> 1) * 32 + (ni & 1) * 16 + l15;
#pragma unroll
        for (int j = 0; j < 4; j++) {
          if (MODE == 1)
            ((float*)Cb)[(size_t)(r + j) * 2048 + cc] = acc[mh * 4 + mi][ni][j];
          else
            ((__bf16*)Cb)[(size_t)(r + j) * 2048 + cc] = (__bf16)acc[mh * 4 + mi][ni][j];
        }
      }
    }
#undef STAGE
#undef LDA
#undef LDB
#undef MMA
}

// ---------- C(MxN) = A(MxK) @ B^T(NxK), bf16 in, fp32 acc (output projection) ----------
// R2-proven structure; NI=4 -> 128x128 tiles (256 blocks, all-resident).
template <int NI, bool F32OUT>
__global__ __launch_bounds__(256, 2) void gemm_bt_kernel(
    const __bf16* __restrict__ A, const __bf16* __restrict__ B,
    void* __restrict__ Cv, int M, int N, int Kd) {
  constexpr int BN = NI * 32;
  __shared__ __bf16 Asm[2][128 * 32];
  __shared__ __bf16 Bsm[2][BN * 32];
  const int tid = threadIdx.x;
  const int lane = tid & 63, wave = tid >> 6;
  const int quad = lane >> 4, l15 = lane & 15;
  const int m0 = blockIdx.x * 128, n0 = blockIdx.y * BN;
  const int wm = (wave & 1) * 64, wn = (wave >> 1) * (NI * 16);
  f32x4 acc[4][NI];
#pragma unroll
  for (int i = 0; i < 4; i++)
#pragma unroll
    for (int j = 0; j < NI; j++) acc[i][j] = (f32x4){0.f, 0.f, 0.f, 0.f};

  const int rA = lane >> 2, cA = (lane & 3) * 8;

  // prologue: stage k0=0 into buf 0
#pragma unroll
  for (int c = wave; c < 8; c += 4)
    load_lds16(A + (size_t)(m0 + c * 16 + rA) * Kd + cA, &Asm[0][c * 512]);
#pragma unroll
  for (int c = wave; c < BN / 16; c += 4)
    load_lds16(B + (size_t)(n0 + c * 16 + rA) * Kd + cA, &Bsm[0][c * 512]);

  for (int k0 = 0; k0 < Kd; k0 += 32) {
    const int buf = (k0 >> 5) & 1;
    __syncthreads();
    if (k0 + 32 < Kd) {
#pragma unroll
      for (int c = wave; c < 8; c += 4)
        load_lds16(A + (size_t)(m0 + c * 16 + rA) * Kd + k0 + 32 + cA, &Asm[buf ^ 1][c * 512]);
#pragma unroll
      for (int c = wave; c < BN / 16; c += 4)
        load_lds16(B + (size_t)(n0 + c * 16 + rA) * Kd + k0 + 32 + cA, &Bsm[buf ^ 1][c * 512]);
    }
    bf16x8 af[4], bfr[NI];
#pragma unroll
    for (int i = 0; i < 4; i++)
      af[i] = *(const bf16x8*)(&Asm[buf][(wm + i * 16 + l15) * 32 + quad * 8]);
#pragma unroll
    for (int i = 0; i < NI; i++)
      bfr[i] = *(const bf16x8*)(&Bsm[buf][(wn + i * 16 + l15) * 32 + quad * 8]);
#pragma unroll
    for (int mi = 0; mi < 4; mi++)
#pragma unroll
      for (int ni = 0; ni < NI; ni++)
        acc[mi][ni] = __builtin_amdgcn_mfma_f32_16x16x32_bf16(af[mi], bfr[ni], acc[mi][ni], 0, 0, 0);
  }
#pragma unroll
  for (int mi = 0; mi < 4; mi++) {
    int r = m0 + wm + mi * 16 + quad * 4;
#pragma unroll
    for (int ni = 0; ni < NI; ni++) {
      int cc = n0 + wn + ni * 16 + l15;
#pragma unroll
      for (int j = 0; j < 4; j++) {
        if (F32OUT)
          ((float*)Cv)[(size_t)(r + j) * N + cc] = acc[mi][ni][j];
        else
          ((__bf16*)Cv)[(size_t)(r + j) * N + cc] = (__bf16)acc[mi][ni][j];
      }
    }
  }
}

// ---------- unified RMSNorm (+RoPE) for Q, K, V in one launch ----------
// R3: V branch writes normalized V back to KVp (coalesced); VT produced by vtrans_kernel.
__global__ void norm_all_kernel(__bf16* __restrict__ Qp, __bf16* __restrict__ KVp,
                                const float* __restrict__ cosb, const float* __restrict__ sinb,
                                const float* __restrict__ qw, const float* __restrict__ kw,
                                const float* __restrict__ vw) {
  const int gw = (blockIdx.x * 256 + threadIdx.x) >> 6;
  const int lane = threadIdx.x & 63;
  const int d0 = lane * 4;

  __bf16* row;
  const float* w;
  int pos = -1;
  bool isV = false;
  float prescale = 1.f;
  if (gw < 16384) {
    int t = gw >> 3, h = gw & 7;
    row = Qp + (size_t)t * 2048 + h * 256;
    w = qw; pos = t + 2048; prescale = 0.0625f;
  } else {
    int g2 = gw - 16384;
    int t = g2 >> 3, r = g2 & 7;
    if (r < 4) {
      row = KVp + (size_t)t * 2048 + r * 256;
      w = kw; pos = t;
    } else {
      row = KVp + (size_t)t * 2048 + 1024 + (r - 4) * 256;
      w = vw; isV = true;
    }
  }

  bf16x4 rv = *(const bf16x4*)(row + d0);
  float x[4];
  float ss = 0.f;
#pragma unroll
  for (int j = 0; j < 4; j++) { x[j] = (float)rv[j]; ss += x[j] * x[j]; }
#pragma unroll
  for (int off = 1; off < 64; off <<= 1) ss += __shfl_xor(ss, off);
  float scale = rsqrtf(ss * (1.f / 256.f) + 1e-6f);
  float n[4];
#pragma unroll
  for (int j = 0; j < 4; j++) n[j] = x[j] * scale * (1.f + w[d0 + j]);

  if (!isV) {
    const float* cp = cosb + (size_t)pos * 256 + d0;
    const float* sp = sinb + (size_t)pos * 256 + d0;
    bf16x4 ov;
#pragma unroll
    for (int j = 0; j < 4; j++) {
      float other = __shfl_xor(n[j], 32);           // d and d^128 live in lane^32
      float rot = (lane < 32) ? -other : other;     // rotate_half sign
      ov[j] = (__bf16)((n[j] * cp[j] + rot * sp[j]) * prescale);
    }
    *(bf16x4*)(row + d0) = ov;
  } else {
    bf16x4 ov;
#pragma unroll
    for (int j = 0; j < 4; j++) ov[j] = (__bf16)n[j];
    *(bf16x4*)(row + d0) = ov;
  }
}

// ---------- V transpose: KVp[t][1024 + h*256 + d] -> VT[h][d][t], 64x64 LDS tiles ----------
// R4: pad 72 (144B rows) keeps all bf16x8 LDS accesses 16B-aligned.
__global__ void vtrans_kernel(const __bf16* __restrict__ KVp, __bf16* __restrict__ VT) {
  __shared__ __bf16 tile[64][72];
  const int b = blockIdx.x;        // 1024 = 4 heads * 64 t-tiles * 4 d-tiles
  const int h = b >> 8;
  const int r = b & 255;
  const int t0 = (r >> 2) * 64;
  const int d0 = (r & 3) * 64;
  const __bf16* src = KVp + 1024 + h * 256 + d0;
#pragma unroll
  for (int it = 0; it < 2; it++) {
    int idx = it * 256 + threadIdx.x;
    int tt = idx >> 3, dd = (idx & 7) * 8;
    *(bf16x8*)(&tile[tt][dd]) = *(const bf16x8*)(src + (size_t)(t0 + tt) * 2048 + dd);
  }
  __syncthreads();
  __bf16* dst = VT + (size_t)h * (256 * 4096) + (size_t)d0 * 4096 + t0;
#pragma unroll
  for (int it = 0; it < 2; it++) {
    int idx = it * 256 + threadIdx.x;
    int dd = idx >> 3, tt = (idx & 7) * 8;
    bf16x8 o;
#pragma unroll
    for (int j = 0; j < 8; j++) o[j] = tile[tt + j][dd];
    *(bf16x8*)(dst + (size_t)dd * 4096 + tt) = o;
  }
}

// ---------- flash attention, fixed softmax max (softcap bounds logits to +-50) ----------
// 512 blocks; (b, b+256) co-reside on a CU -> qt remap pairs long+short tiles (49 steps/CU).
// KV-split x4 is INTERLEAVED: sp processes steps s = 4i+sp (t0=(4i+sp)*32), so all
// resident blocks on an XCD walk the same ~128-key window together -> K/V stays L2-hot.
// Causal mask: each sp's LAST step is its diagonal step (s=T-4+sp).
// R1: K/V LDS tiles XOR-swizzled (conflicts 6.8M -> 0.4M). R2: no setprio (lockstep waves).
// R7: V-direct-from-global REVERTED (R6: latency exposure at 2 waves/SIMD halved speed).
__global__ __launch_bounds__(256, 2) void attn_kernel(
    const __bf16* __restrict__ Q,   // [2048][8*256] post norm+rope, prescaled 2^-4
    const __bf16* __restrict__ K,   // [4096][2048] cols 0..1023 = K heads (post norm+rope)
    const __bf16* __restrict__ VT,  // [4][256][4096] post norm, transposed
    _Float16* __restrict__ Op,      // [4][2048][2048] normalized partial O (fp16)
    float* __restrict__ Lp) {       // [4][2048][8]    partial l (fp32)
  __shared__ __bf16 Ksm[2][8][32][32];  // 32 KB  [buf][d-panel][key][d]   (swizzled)
  __shared__ __bf16 Vsm[2][256][32];    // 32 KB  [buf][d][key]            (swizzled)
  __shared__ __bf16 Pex[4][32][40];     // 10 KB  per-wave P C->A exchange
  const int tid = threadIdx.x;
  const int lane = tid & 63, wave = tid >> 6;
  const int quad = lane >> 4, l15 = lane & 15;
  const int b = blockIdx.x;
  const int idx = b & 255;
  const int h = idx & 7, sp = (idx >> 3) & 3;
  int qt = idx >> 5;                    // 0..7
  if (b >= 256) qt = 15 - qt;           // long-short pairing on co-resident CUs
  const int kvh = h >> 1;

  const int T = 68 + 4 * qt;            // total 32-key steps; T % 4 == 0 always
  const int nst = T >> 2;               // this split handles s = sp, sp+4, ..., T-4+sp

  bf16x8 qf[2][8];
#pragma unroll
  for (int r = 0; r < 2; r++) {
    const __bf16* qp = Q + (size_t)(qt * 128 + wave * 32 + r * 16 + l15) * 2048 + h * 256 + quad * 8;
#pragma unroll
    for (int s = 0; s < 8; s++) qf[r][s] = *(const bf16x8*)(qp + s * 32);
  }
  f32x4 o[2][16];
#pragma unroll
  for (int r = 0; r < 2; r++)
#pragma unroll
    for (int i = 0; i < 16; i++) o[r][i] = (f32x4){0.f, 0.f, 0.f, 0.f};
  float rs[2][4] = {{0.f, 0.f, 0.f, 0.f}, {0.f, 0.f, 0.f, 0.f}};

  const __bf16* Kb = K + kvh * 256;
  const __bf16* Vb = VT + (size_t)kvh * (256 * 4096);
  const int rA = lane >> 2;
  // swizzled source column: LDS slot (lane&3) of row rA gets global slot (lane&3)^((rA>>1)&3)
  const int cAs = (((lane & 3) ^ ((rA >> 1) & 3)) * 8);
  // swizzled read column
  const int kx = (quad ^ ((l15 >> 1) & 3)) * 8;
  const int qbase = 2048 + qt * 128 + wave * 32 + quad * 4;  // + r*16 + j

  // stage step s=sp into buf 0
  {
    const int t0 = sp * 32;
#pragma unroll
    for (int ch = 0; ch < 4; ch++) {
      int cc = wave + ch * 4;
      int s = cc >> 1, hf = cc & 1;
      load_lds16(Kb + (size_t)(t0 + hf * 16 + rA) * 2048 + s * 32 + cAs, &Ksm[0][s][hf * 16][0]);
      load_lds16(Vb + (size_t)(cc * 16 + rA) * 4096 + t0 + cAs, &Vsm[0][cc * 16][0]);
    }
  }

  for (int i = 0; i < nst; i++) {
    const int buf = i & 1;
    const int t0 = (4 * i + sp) * 32;
    __syncthreads();  // buf ready; all waves done with other buf
    if (i + 1 < nst) {
      const int t1 = t0 + 128;
#pragma unroll
      for (int ch = 0; ch < 4; ch++) {
        int cc = wave + ch * 4;
        int s = cc >> 1, hf = cc & 1;
        load_lds16(Kb + (size_t)(t1 + hf * 16 + rA) * 2048 + s * 32 + cAs, &Ksm[buf ^ 1][s][hf * 16][0]);
        load_lds16(Vb + (size_t)(cc * 16 + rA) * 4096 + t1 + cAs, &Vsm[buf ^ 1][cc * 16][0]);
      }
    }

    // S = Q K^T : 32q x 32k per wave; each K B-frag feeds 2 MFMAs (r=0,1)
    f32x4 s4[2][2];
    s4[0][0] = (f32x4){0.f, 0.f, 0.f, 0.f};
    s4[0][1] = s4[0][0]; s4[1][0] = s4[0][0]; s4[1][1] = s4[0][0];
#pragma unroll
    for (int s = 0; s < 8; s++) {
      bf16x8 b0 = *(const bf16x8*)(&Ksm[buf][s][l15][kx]);
      bf16x8 b1 = *(const bf16x8*)(&Ksm[buf][s][16 + l15][kx]);
      s4[0][0] = __builtin_amdgcn_mfma_f32_16x16x32_bf16(qf[0][s], b0, s4[0][0], 0, 0, 0);
      s4[0][1] = __builtin_amdgcn_mfma_f32_16x16x32_bf16(qf[0][s], b1, s4[0][1], 0, 0, 0);
      s4[1][0] = __builtin_amdgcn_mfma_f32_16x16x32_bf16(qf[1][s], b0, s4[1][0], 0, 0, 0);
      s4[1][1] = __builtin_amdgcn_mfma_f32_16x16x32_bf16(qf[1][s], b1, s4[1][1], 0, 0, 0);
    }

    // p = exp(50*tanh(v/50) - 50) = exp(-100/(e^{0.04v}+1)); max pinned at 50.
    const bool mk = (i == nst - 1);     // diagonal step for this sp
#pragma unroll
    for (int r = 0; r < 2; r++)
#pragma unroll
      for (int nt = 0; nt < 2; nt++) {
        const int key = t0 + nt * 16 + l15;
#pragma unroll
        for (int j = 0; j < 4; j++) {
          float v = s4[r][nt][j];
          float e = __expf(v * 0.04f);
          float p = __expf(-100.f * __builtin_amdgcn_rcpf(e + 1.f));
          if (mk && key > qbase + r * 16 + j) p = 0.f;
          s4[r][nt][j] = p;
          rs[r][j] += p;  // per-lane partial; cross-lane reduce at end
        }
      }

    // P: C-layout -> LDS -> A-layout (per-wave slab)
#pragma unroll
    for (int r = 0; r < 2; r++)
#pragma unroll
      for (int nt = 0; nt < 2; nt++)
#pragma unroll
        for (int j = 0; j < 4; j++)
          Pex[wave][r * 16 + quad * 4 + j][nt * 16 + l15] = (__bf16)s4[r][nt][j];

    bf16x8 pf0 = *(const bf16x8*)(&Pex[wave][l15][quad * 8]);
    bf16x8 pf1 = *(const bf16x8*)(&Pex[wave][16 + l15][quad * 8]);
#pragma unroll
    for (int d = 0; d < 16; d++) {
      bf16x8 vf = *(const bf16x8*)(&Vsm[buf][d * 16 + l15][kx]);
      o[0][d] = __builtin_amdgcn_mfma_f32_16x16x32_bf16(pf0, vf, o[0][d], 0, 0, 0);
      o[1][d] = __builtin_amdgcn_mfma_f32_16x16x32_bf16(pf1, vf, o[1][d], 0, 0, 0);
    }
  }

  // reduce row-sums over the 16 key-columns held across l15 lanes
#pragma unroll
  for (int off = 1; off < 16; off <<= 1)
#pragma unroll
    for (int r = 0; r < 2; r++)
#pragma unroll
      for (int j = 0; j < 4; j++) rs[r][j] += __shfl_xor(rs[r][j], off);

  _Float16* Os = Op + (size_t)sp * (2048 * 2048);
  float* Ls = Lp + sp * (2048 * 8);
#pragma unroll
  for (int r = 0; r < 2; r++) {
    float inv[4];
#pragma unroll
    for (int j = 0; j < 4; j++)
      inv[j] = rs[r][j] > 0.f ? 1.f / rs[r][j] : 0.f;
    const int trow = qt * 128 + wave * 32 + r * 16 + quad * 4;
#pragma unroll
    for (int d = 0; d < 16; d++) {
      const int col = h * 256 + d * 16 + l15;
#pragma unroll
      for (int j = 0; j < 4; j++)
        Os[(size_t)(trow + j) * 2048 + col] = (_Float16)(o[r][d][j] * inv[j]);
    }
    if (l15 == 0) {
#pragma unroll
      for (int j = 0; j < 4; j++) Ls[(trow + j) * 8 + h] = rs[r][j];
    }
  }
}

// ---------- merge: O = sum(l_i * Onorm_i) / sum(l_i) ----------
__global__ void merge_kernel(const _Float16* __restrict__ Op, const float* __restrict__ Lp,
                             __bf16* __restrict__ AO) {
  int f = (blockIdx.x * 256 + threadIdx.x) * 4;
  int q = f >> 11, col = f & 2047, h = col >> 8;
  float lsum = 0.f;
  float acc[4] = {0.f, 0.f, 0.f, 0.f};
#pragma unroll
  for (int s = 0; s < 4; s++) {
    float l = Lp[s * (2048 * 8) + q * 8 + h];
    lsum += l;
    f16x4 v = *(const f16x4*)(Op + (size_t)s * (2048 * 2048) + f);
#pragma unroll
    for (int j = 0; j < 4; j++) acc[j] += l * (float)v[j];
  }
  float inv = 1.f / lsum;
  bf16x4 o;
#pragma unroll
  for (int j = 0; j < 4; j++) o[j] = (__bf16)(acc[j] * inv);
  *(bf16x4*)(AO + f) = o;
}

extern "C" void kernel_launch(void* const* d_in, const int* in_sizes, int n_in,
                              void* d_out, int out_size, void* d_ws, size_t ws_size,
                              hipStream_t stream) {
  const float* hidden = (const float*)d_in[0];
  const float* cosb = (const float*)d_in[1];
  const float* sinb = (const float*)d_in[2];
  // d_in[3] attention_mask: causal, reproduced analytically
  const float* wq = (const float*)d_in[4];
  const float* wk = (const float*)d_in[5];
  const float* wv = (const float*)d_in[6];
  const float* wo = (const float*)d_in[7];
  const float* qw = (const float*)d_in[8];
  const float* kw = (const float*)d_in[9];
  const float* vw = (const float*)d_in[10];
  float* outp = (float*)d_out;

  char* p = (char*)d_ws;
  __bf16* Xb = (__bf16*)p;   p += (size_t)SEQL * HID * 2;       // 16 MB (dead after GEMMs)
  __bf16* WQT = (__bf16*)p;  p += (size_t)2048 * 2048 * 2;      // 8 MB  (dead after Q GEMM)
  __bf16* WKVT = (__bf16*)p; p += (size_t)2048 * 2048 * 2;      // 8 MB  (dead after KV GEMM)
  __bf16* WOT = (__bf16*)p;  p += (size_t)2048 * 2048 * 2;      // 8 MB
  __bf16* Qp = (__bf16*)p;   p += (size_t)2048 * 2048 * 2;      // 8 MB
  __bf16* KVp = (__bf16*)p;  p += (size_t)4096 * 2048 * 2;      // 16 MB
  __bf16* VT = (__bf16*)p;   p += (size_t)4 * 256 * 4096 * 2;   // 8 MB
  __bf16* AO = (__bf16*)p;   p += (size_t)2048 * 2048 * 2;      // 8 MB
  float* Lpart = (float*)p;  p += (size_t)4 * 2048 * 8 * 4;     // 256 KB (total ~80.3 MB)
  // fp16 normalized partial O (4 x 8 MB = 32 MB) overlays the dead
  // Xb(16)+WQT(8)+WKVT(8) regions (contiguous, end exactly at WOT).
  _Float16* Opart = (_Float16*)Xb;

  // 1) fused prep: X convert + all weight transposes (one launch)
  prep_kernel<<<11264, 256, 0, stream>>>(hidden, Xb, wq, wk, wv, wo, WQT, WKVT, WOT);

  // 2) fused Q + KV projections: 192 blocks of 256x256 (128 KV + 64 Q), 512 threads
  gemm256_kernel<0><<<192, 512, 0, stream>>>(Xb, WKVT, WQT, KVp, Qp);

  // 3) unified RMSNorm (+RoPE); V written back coalesced, then tiled transpose -> VT
  norm_all_kernel<<<12288, 256, 0, stream>>>(Qp, KVp, cosb, sinb, qw, kw, vw);
  vtrans_kernel<<<1024, 256, 0, stream>>>(KVp, VT);

  // 4) flash attention, interleaved KV-split x4 (L2-hot), fp16 normalized partials
  attn_kernel<<<512, 256, 0, stream>>>(Qp, KVp, VT, Opart, Lpart);
  merge_kernel<<<4096, 256, 0, stream>>>(Opart, Lpart, AO);

  // 5) output projection -> fp32 (128x128 tiles, 256 blocks, 2/CU)
  gemm_bt_kernel<4, true><<<dim3(16, 16), 256, 0, stream>>>(AO, WOT, outp, 2048, 2048, 2048);
}

// Round 9
// 355.535 us; speedup vs baseline: 1.2916x; 1.0176x over previous
//
#include <hip/hip_runtime.h>

// Fixed problem sizes
#define HID 2048
#define SEQL 4096
#define CHUNK 2048
#define NHEADS 8
#define NKVH 4
#define HDIM 256

typedef __bf16 bf16x4 __attribute__((ext_vector_type(4)));
typedef __bf16 bf16x8 __attribute__((ext_vector_type(8)));
typedef float f32x4 __attribute__((ext_vector_type(4)));
typedef _Float16 f16x4 __attribute__((ext_vector_type(4)));
typedef __attribute__((address_space(1))) unsigned int* as1_u32;
typedef __attribute__((address_space(3))) unsigned int* as3_u32;

// async global->LDS, 16B per lane; LDS dest = wave-uniform base + lane*16
__device__ __forceinline__ void load_lds16(const __bf16* g, __bf16* l) {
  __builtin_amdgcn_global_load_lds((as1_u32)g, (as3_u32)l, 16, 0, 0);
}

// ---------- fused prep: fp32->bf16 convert of X + all 4 weight transposes ----------
__global__ void prep_kernel(const float* __restrict__ X, __bf16* __restrict__ Y,
                            const float* __restrict__ wq, const float* __restrict__ wk,
                            const float* __restrict__ wv, const float* __restrict__ wo,
                            __bf16* __restrict__ WQT, __bf16* __restrict__ WKVT,
                            __bf16* __restrict__ WOT) {
  if (blockIdx.x < 8192) {
    int i = blockIdx.x * blockDim.x + threadIdx.x;
    const float4* xv = (const float4*)X;
    float4 v = xv[i];
    bf16x4 o;
    o[0] = (__bf16)v.x; o[1] = (__bf16)v.y; o[2] = (__bf16)v.z; o[3] = (__bf16)v.w;
    *(bf16x4*)(Y + i * 4) = o;
    return;
  }
  __shared__ float tile[64][65];
  const int b = blockIdx.x - 8192;
  const float* W;
  __bf16* WT;
  int R, C, bx, by;
  if (b < 1024) { W = wq; WT = WQT; R = 2048; C = 2048; bx = b & 31; by = b >> 5; }
  else if (b < 1536) { int q = b - 1024; W = wk; WT = WKVT; R = 2048; C = 1024; bx = q & 15; by = q >> 4; }
  else if (b < 2048) { int q = b - 1536; W = wv; WT = WKVT + (size_t)1024 * 2048; R = 2048; C = 1024; bx = q & 15; by = q >> 4; }
  else { int q = b - 2048; W = wo; WT = WOT; R = 2048; C = 2048; bx = q & 31; by = q >> 5; }
  int r0 = by * 64, c0 = bx * 64;
#pragma unroll
  for (int it = 0; it < 4; it++) {
    int idx = it * 256 + threadIdx.x;           // 1024 float4 = 64x64 f32
    int r = idx >> 4, c4 = (idx & 15) * 4;
    float4 v = *(const float4*)&W[(size_t)(r0 + r) * C + c0 + c4];
    tile[r][c4] = v.x; tile[r][c4 + 1] = v.y; tile[r][c4 + 2] = v.z; tile[r][c4 + 3] = v.w;
  }
  __syncthreads();
#pragma unroll
  for (int it = 0; it < 2; it++) {
    int idx = it * 256 + threadIdx.x;           // 512 bf16x8 = 64x64 bf16
    int cc = idx >> 3, rb = (idx & 7) * 8;
    bf16x8 o;
#pragma unroll
    for (int j = 0; j < 8; j++) o[j] = (__bf16)tile[rb + j][cc];
    *(bf16x8*)&WT[(size_t)(c0 + cc) * R + r0 + rb] = o;
  }
}

// ---------- 256x256-tile GEMM, 8 waves (2M x 4N), BK=64, counted-vmcnt pipeline ----------
// R5 structure (passed): 2 barriers per K-tile, straight-line ds_read+MFMA region,
// counted vmcnt(8) -- never drained to 0 in the loop. LDS XOR-swizzle slot^=(row&7)
// via pre-swizzled GLOBAL source + swizzled ds_read (rule #21 both-sides).
template <int MODE>
__global__ __launch_bounds__(512, 2) void gemm256_kernel(
    const __bf16* __restrict__ A0, const __bf16* __restrict__ B0,
    const __bf16* __restrict__ B1, void* __restrict__ C0, void* __restrict__ C1) {
  __shared__ __bf16 Asm[2][256 * 64];  // 64 KB
  __shared__ __bf16 Bsm[2][256 * 64];  // 64 KB
  const int tid = threadIdx.x;
  const int lane = tid & 63, wave = tid >> 6;
  const int quad = lane >> 4, l15 = lane & 15;
  const int wm = (wave & 1) * 128, wn = (wave >> 1) * 64;

  const __bf16 *A, *B;
  char* Cb;
  int m0, n0;
  if (MODE == 0) {
    int b = blockIdx.x;
    if (b < 128) { A = A0; B = B0; Cb = (char*)C0; m0 = (b & 15) * 256; n0 = (b >> 4) * 256; }
    else { int q = b - 128; A = A0 + (size_t)2048 * 2048; B = B1; Cb = (char*)C1; m0 = (q & 7) * 256; n0 = (q >> 3) * 256; }
  } else {
    A = A0; B = B0; Cb = (char*)C0;
    m0 = (int)(blockIdx.x & 7) * 256; n0 = (int)(blockIdx.x >> 3) * 256;
  }

  f32x4 acc[8][4];
#pragma unroll
  for (int i = 0; i < 8; i++)
#pragma unroll
    for (int j = 0; j < 4; j++) acc[i][j] = (f32x4){0.f, 0.f, 0.f, 0.f};

  const int rr = tid >> 3;
  const int gch = (tid & 7) ^ ((tid >> 3) & 7);
  const int ldsb = wave * 512;  // wave-uniform LDS elem base within each 64-row group

  const int sx = l15 & 7;
  const int s0 = ((0 + quad) ^ sx) * 8;
  const int s1 = ((4 + quad) ^ sx) * 8;

#define STAGE(T, BF)                                                                  \
  {                                                                                   \
    const int k0s = (T) * 64;                                                         \
    _Pragma("unroll")                                                                 \
    for (int a = 0; a < 4; a++) {                                                     \
      load_lds16(A + (size_t)(m0 + a * 64 + rr) * 2048 + k0s + gch * 8,               \
                 &Asm[BF][a * 4096 + ldsb]);                                          \
      load_lds16(B + (size_t)(n0 + a * 64 + rr) * 2048 + k0s + gch * 8,               \
                 &Bsm[BF][a * 4096 + ldsb]);                                          \
    }                                                                                 \
  }

#define LDA(MH, BF)                                                                   \
  _Pragma("unroll")                                                                   \
  for (int mi = 0; mi < 4; mi++) {                                                    \
    const int rowb = (wm + (MH) * 64 + mi * 16 + l15) * 64;                           \
    af[mi * 2 + 0] = *(const bf16x8*)(&Asm[BF][rowb + s0]);                           \
    af[mi * 2 + 1] = *(const bf16x8*)(&Asm[BF][rowb + s1]);                           \
  }

#define LDB(DST, NH, BF)                                                              \
  _Pragma("unroll")                                                                   \
  for (int ni = 0; ni < 2; ni++) {                                                    \
    const int rowb = (wn + (NH) * 32 + ni * 16 + l15) * 64;                           \
    DST[ni * 2 + 0] = *(const bf16x8*)(&Bsm[BF][rowb + s0]);                          \
    DST[ni * 2 + 1] = *(const bf16x8*)(&Bsm[BF][rowb + s1]);                          \
  }

#define MMA(MH, NH, BV)                                                               \
  _Pragma("unroll")                                                                   \
  for (int mi = 0; mi < 4; mi++)                                                      \
    _Pragma("unroll")                                                                 \
    for (int ni = 0; ni < 2; ni++) {                                                  \
      acc[(MH) * 4 + mi][(NH) * 2 + ni] = __builtin_amdgcn_mfma_f32_16x16x32_bf16(    \
          af[mi * 2 + 0], BV[ni * 2 + 0], acc[(MH) * 4 + mi][(NH) * 2 + ni], 0, 0, 0);\
      acc[(MH) * 4 + mi][(NH) * 2 + ni] = __builtin_amdgcn_mfma_f32_16x16x32_bf16(    \
          af[mi * 2 + 1], BV[ni * 2 + 1], acc[(MH) * 4 + mi][(NH) * 2 + ni], 0, 0, 0);\
    }

  bf16x8 af[8], bX[4], bY[4];

  STAGE(0, 0);
  STAGE(1, 1);
  asm volatile("s_waitcnt vmcnt(8)" ::: "memory");  // tile0 landed; tile1 in flight
  __builtin_amdgcn_s_barrier();

  const int NT = 32;  // K = 2048 / BK = 64
#pragma unroll 2
  for (int t = 0; t < NT; t++) {
    const int c = t & 1;
    LDA(0, c);
    LDB(bX, 0, c);
    LDB(bY, 1, c);
    MMA(0, 0, bX);
    MMA(0, 1, bY);
    LDA(1, c);
    MMA(1, 1, bY);
    MMA(1, 0, bX);
    __builtin_amdgcn_s_barrier();  // all waves done reading buf c -> safe to restage it
    if (t + 2 < NT) {
      STAGE(t + 2, c);
      asm volatile("s_waitcnt vmcnt(8)" ::: "memory");  // t+1 complete; t+2 in flight
      __builtin_amdgcn_s_barrier();
    } else if (t + 1 < NT) {
      asm volatile("s_waitcnt vmcnt(0)" ::: "memory");  // tail: drain last tile
      __builtin_amdgcn_s_barrier();
    }
  }

#pragma unroll
  for (int mh = 0; mh < 2; mh++)
#pragma unroll
    for (int mi = 0; mi < 4; mi++) {
      const int r = m0 + wm + mh * 64 + mi * 16 + quad * 4;
#pragma unroll
      for (int ni = 0; ni < 4; ni++) {
        const int cc = n0 + wn + (ni >> 1) * 32 + (ni & 1) * 16 + l15;
#pragma unroll
        for (int j = 0; j < 4; j++) {
          if (MODE == 1)
            ((float*)Cb)[(size_t)(r + j) * 2048 + cc] = acc[mh * 4 + mi][ni][j];
          else
            ((__bf16*)Cb)[(size_t)(r + j) * 2048 + cc] = (__bf16)acc[mh * 4 + mi][ni][j];
        }
      }
    }
#undef STAGE
#undef LDA
#undef LDB
#undef MMA
}

// ---------- C(MxN) = A(MxK) @ B^T(NxK), bf16 in, fp32 acc (output projection) ----------
// R9: counted-vmcnt pipeline (T4, proven in gemm256 R5): stage t+2 after the read-done
// barrier, s_waitcnt vmcnt(4) retires exactly tile t+1's 4 loads/thread (2 A + 2 B at
// NI=4), never 0 mid-loop. K-accumulation order identical -> bit-identical fp32 out.
template <int NI, bool F32OUT>
__global__ __launch_bounds__(256, 2) void gemm_bt_kernel(
    const __bf16* __restrict__ A, const __bf16* __restrict__ B,
    void* __restrict__ Cv, int M, int N, int Kd) {
  constexpr int BN = NI * 32;
  static_assert(NI == 4, "vmcnt literals assume 4 loads/thread per stage");
  __shared__ __bf16 Asm[2][128 * 32];
  __shared__ __bf16 Bsm[2][BN * 32];
  const int tid = threadIdx.x;
  const int lane = tid & 63, wave = tid >> 6;
  const int quad = lane >> 4, l15 = lane & 15;
  const int m0 = blockIdx.x * 128, n0 = blockIdx.y * BN;
  const int wm = (wave & 1) * 64, wn = (wave >> 1) * (NI * 16);
  f32x4 acc[4][NI];
#pragma unroll
  for (int i = 0; i < 4; i++)
#pragma unroll
    for (int j = 0; j < NI; j++) acc[i][j] = (f32x4){0.f, 0.f, 0.f, 0.f};

  const int rA = lane >> 2, cA = (lane & 3) * 8;

  // prologue: stage tiles 0 and 1 (4 loads/thread each; 8 outstanding)
#pragma unroll
  for (int c = wave; c < 8; c += 4)
    load_lds16(A + (size_t)(m0 + c * 16 + rA) * Kd + cA, &Asm[0][c * 512]);
#pragma unroll
  for (int c = wave; c < BN / 16; c += 4)
    load_lds16(B + (size_t)(n0 + c * 16 + rA) * Kd + cA, &Bsm[0][c * 512]);
#pragma unroll
  for (int c = wave; c < 8; c += 4)
    load_lds16(A + (size_t)(m0 + c * 16 + rA) * Kd + 32 + cA, &Asm[1][c * 512]);
#pragma unroll
  for (int c = wave; c < BN / 16; c += 4)
    load_lds16(B + (size_t)(n0 + c * 16 + rA) * Kd + 32 + cA, &Bsm[1][c * 512]);
  asm volatile("s_waitcnt vmcnt(4)" ::: "memory");  // tile0 landed; tile1 in flight
  __builtin_amdgcn_s_barrier();

  const int NT = Kd >> 5;
  for (int t = 0; t < NT; t++) {
    const int buf = t & 1;
    bf16x8 af[4], bfr[NI];
#pragma unroll
    for (int i = 0; i < 4; i++)
      af[i] = *(const bf16x8*)(&Asm[buf][(wm + i * 16 + l15) * 32 + quad * 8]);
#pragma unroll
    for (int i = 0; i < NI; i++)
      bfr[i] = *(const bf16x8*)(&Bsm[buf][(wn + i * 16 + l15) * 32 + quad * 8]);
#pragma unroll
    for (int mi = 0; mi < 4; mi++)
#pragma unroll
      for (int ni = 0; ni < NI; ni++)
        acc[mi][ni] = __builtin_amdgcn_mfma_f32_16x16x32_bf16(af[mi], bfr[ni], acc[mi][ni], 0, 0, 0);
    __builtin_amdgcn_s_barrier();  // all waves done reading buf -> safe to restage it
    if (t + 2 < NT) {
      const int kn = (t + 2) * 32;
#pragma unroll
      for (int c = wave; c < 8; c += 4)
        load_lds16(A + (size_t)(m0 + c * 16 + rA) * Kd + kn + cA, &Asm[buf][c * 512]);
#pragma unroll
      for (int c = wave; c < BN / 16; c += 4)
        load_lds16(B + (size_t)(n0 + c * 16 + rA) * Kd + kn + cA, &Bsm[buf][c * 512]);
      asm volatile("s_waitcnt vmcnt(4)" ::: "memory");  // t+1 complete; t+2 in flight
      __builtin_amdgcn_s_barrier();
    } else if (t + 1 < NT) {
      asm volatile("s_waitcnt vmcnt(0)" ::: "memory");  // tail: drain last tile
      __builtin_amdgcn_s_barrier();
    }
  }
#pragma unroll
  for (int mi = 0; mi < 4; mi++) {
    int r = m0 + wm + mi * 16 + quad * 4;
#pragma unroll
    for (int ni = 0; ni < NI; ni++) {
      int cc = n0 + wn + ni * 16 + l15;
#pragma unroll
      for (int j = 0; j < 4; j++) {
        if (F32OUT)
          ((float*)Cv)[(size_t)(r + j) * N + cc] = acc[mi][ni][j];
        else
          ((__bf16*)Cv)[(size_t)(r + j) * N + cc] = (__bf16)acc[mi][ni][j];
      }
    }
  }
}

// ---------- unified RMSNorm (+RoPE) for Q, K, V in one launch ----------
__global__ void norm_all_kernel(__bf16* __restrict__ Qp, __bf16* __restrict__ KVp,
                                const float* __restrict__ cosb, const float* __restrict__ sinb,
                                const float* __restrict__ qw, const float* __restrict__ kw,
                                const float* __restrict__ vw) {
  const int gw = (blockIdx.x * 256 + threadIdx.x) >> 6;
  const int lane = threadIdx.x & 63;
  const int d0 = lane * 4;

  __bf16* row;
  const float* w;
  int pos = -1;
  bool isV = false;
  float prescale = 1.f;
  if (gw < 16384) {
    int t = gw >> 3, h = gw & 7;
    row = Qp + (size_t)t * 2048 + h * 256;
    w = qw; pos = t + 2048; prescale = 0.0625f;
  } else {
    int g2 = gw - 16384;
    int t = g2 >> 3, r = g2 & 7;
    if (r < 4) {
      row = KVp + (size_t)t * 2048 + r * 256;
      w = kw; pos = t;
    } else {
      row = KVp + (size_t)t * 2048 + 1024 + (r - 4) * 256;
      w = vw; isV = true;
    }
  }

  bf16x4 rv = *(const bf16x4*)(row + d0);
  float x[4];
  float ss = 0.f;
#pragma unroll
  for (int j = 0; j < 4; j++) { x[j] = (float)rv[j]; ss += x[j] * x[j]; }
#pragma unroll
  for (int off = 1; off < 64; off <<= 1) ss += __shfl_xor(ss, off);
  float scale = rsqrtf(ss * (1.f / 256.f) + 1e-6f);
  float n[4];
#pragma unroll
  for (int j = 0; j < 4; j++) n[j] = x[j] * scale * (1.f + w[d0 + j]);

  if (!isV) {
    const float* cp = cosb + (size_t)pos * 256 + d0;
    const float* sp = sinb + (size_t)pos * 256 + d0;
    bf16x4 ov;
#pragma unroll
    for (int j = 0; j < 4; j++) {
      float other = __shfl_xor(n[j], 32);           // d and d^128 live in lane^32
      float rot = (lane < 32) ? -other : other;     // rotate_half sign
      ov[j] = (__bf16)((n[j] * cp[j] + rot * sp[j]) * prescale);
    }
    *(bf16x4*)(row + d0) = ov;
  } else {
    bf16x4 ov;
#pragma unroll
    for (int j = 0; j < 4; j++) ov[j] = (__bf16)n[j];
    *(bf16x4*)(row + d0) = ov;
  }
}

// ---------- V transpose: KVp[t][1024 + h*256 + d] -> VT[h][d][t], 64x64 LDS tiles ----------
// R4: pad 72 (144B rows) keeps all bf16x8 LDS accesses 16B-aligned.
__global__ void vtrans_kernel(const __bf16* __restrict__ KVp, __bf16* __restrict__ VT) {
  __shared__ __bf16 tile[64][72];
  const int b = blockIdx.x;        // 1024 = 4 heads * 64 t-tiles * 4 d-tiles
  const int h = b >> 8;
  const int r = b & 255;
  const int t0 = (r >> 2) * 64;
  const int d0 = (r & 3) * 64;
  const __bf16* src = KVp + 1024 + h * 256 + d0;
#pragma unroll
  for (int it = 0; it < 2; it++) {
    int idx = it * 256 + threadIdx.x;
    int tt = idx >> 3, dd = (idx & 7) * 8;
    *(bf16x8*)(&tile[tt][dd]) = *(const bf16x8*)(src + (size_t)(t0 + tt) * 2048 + dd);
  }
  __syncthreads();
  __bf16* dst = VT + (size_t)h * (256 * 4096) + (size_t)d0 * 4096 + t0;
#pragma unroll
  for (int it = 0; it < 2; it++) {
    int idx = it * 256 + threadIdx.x;
    int dd = idx >> 3, tt = (idx & 7) * 8;
    bf16x8 o;
#pragma unroll
    for (int j = 0; j < 8; j++) o[j] = tile[tt + j][dd];
    *(bf16x8*)(dst + (size_t)dd * 4096 + tt) = o;
  }
}

// ---------- flash attention, fixed softmax max (softcap bounds logits to +-50) ----------
// 512 blocks; (b, b+256) co-reside on a CU -> qt remap pairs long+short tiles (49 steps/CU).
// KV-split x4 INTERLEAVED (L2-hot window). Causal: each sp's LAST step is its diagonal.
// R1: K/V LDS tiles XOR-swizzled (conflicts 6.8M -> 0.4M). R2: no setprio.
// R9: counted-vmcnt staging (T4). Old __syncthreads drained vmcnt(0), exposing the
//     freshly-issued next-tile loads' full L2/HBM latency every step. Now:
//     barrier (all done reading buf^1) -> issue 8 loads into buf^1 -> vmcnt(8)
//     (current tile's 8 complete; next tile's stay in flight across the whole
//     QK+softmax+PV phase) -> barrier (publish). Last iter: vmcnt(0).
//     Data and MFMA order unchanged -> bit-identical output.
__global__ __launch_bounds__(256, 2) void attn_kernel(
    const __bf16* __restrict__ Q,   // [2048][8*256] post norm+rope, prescaled 2^-4
    const __bf16* __restrict__ K,   // [4096][2048] cols 0..1023 = K heads (post norm+rope)
    const __bf16* __restrict__ VT,  // [4][256][4096] post norm, transposed
    _Float16* __restrict__ Op,      // [4][2048][2048] normalized partial O (fp16)
    float* __restrict__ Lp) {       // [4][2048][8]    partial l (fp32)
  __shared__ __bf16 Ksm[2][8][32][32];  // 32 KB  [buf][d-panel][key][d]   (swizzled)
  __shared__ __bf16 Vsm[2][256][32];    // 32 KB  [buf][d][key]            (swizzled)
  __shared__ __bf16 Pex[4][32][40];     // 10 KB  per-wave P C->A exchange
  const int tid = threadIdx.x;
  const int lane = tid & 63, wave = tid >> 6;
  const int quad = lane >> 4, l15 = lane & 15;
  const int b = blockIdx.x;
  const int idx = b & 255;
  const int h = idx & 7, sp = (idx >> 3) & 3;
  int qt = idx >> 5;                    // 0..7
  if (b >= 256) qt = 15 - qt;           // long-short pairing on co-resident CUs
  const int kvh = h >> 1;

  const int T = 68 + 4 * qt;            // total 32-key steps; T % 4 == 0 always
  const int nst = T >> 2;               // this split handles s = sp, sp+4, ..., T-4+sp

  bf16x8 qf[2][8];
#pragma unroll
  for (int r = 0; r < 2; r++) {
    const __bf16* qp = Q + (size_t)(qt * 128 + wave * 32 + r * 16 + l15) * 2048 + h * 256 + quad * 8;
#pragma unroll
    for (int s = 0; s < 8; s++) qf[r][s] = *(const bf16x8*)(qp + s * 32);
  }
  f32x4 o[2][16];
#pragma unroll
  for (int r = 0; r < 2; r++)
#pragma unroll
    for (int i = 0; i < 16; i++) o[r][i] = (f32x4){0.f, 0.f, 0.f, 0.f};
  float rs[2][4] = {{0.f, 0.f, 0.f, 0.f}, {0.f, 0.f, 0.f, 0.f}};

  const __bf16* Kb = K + kvh * 256;
  const __bf16* Vb = VT + (size_t)kvh * (256 * 4096);
  const int rA = lane >> 2;
  // swizzled source column: LDS slot (lane&3) of row rA gets global slot (lane&3)^((rA>>1)&3)
  const int cAs = (((lane & 3) ^ ((rA >> 1) & 3)) * 8);
  // swizzled read column
  const int kx = (quad ^ ((l15 >> 1) & 3)) * 8;
  const int qbase = 2048 + qt * 128 + wave * 32 + quad * 4;  // + r*16 + j

  // stage step s=sp into buf 0 (8 loads/thread in flight)
  {
    const int t0 = sp * 32;
#pragma unroll
    for (int ch = 0; ch < 4; ch++) {
      int cc = wave + ch * 4;
      int s = cc >> 1, hf = cc & 1;
      load_lds16(Kb + (size_t)(t0 + hf * 16 + rA) * 2048 + s * 32 + cAs, &Ksm[0][s][hf * 16][0]);
      load_lds16(Vb + (size_t)(cc * 16 + rA) * 4096 + t0 + cAs, &Vsm[0][cc * 16][0]);
    }
  }

  for (int i = 0; i < nst; i++) {
    const int buf = i & 1;
    const int t0 = (4 * i + sp) * 32;
    __builtin_amdgcn_s_barrier();   // all waves done reading buf^1 (prev step)
    if (i + 1 < nst) {
      const int t1 = t0 + 128;
#pragma unroll
      for (int ch = 0; ch < 4; ch++) {
        int cc = wave + ch * 4;
        int s = cc >> 1, hf = cc & 1;
        load_lds16(Kb + (size_t)(t1 + hf * 16 + rA) * 2048 + s * 32 + cAs, &Ksm[buf ^ 1][s][hf * 16][0]);
        load_lds16(Vb + (size_t)(cc * 16 + rA) * 4096 + t1 + cAs, &Vsm[buf ^ 1][cc * 16][0]);
      }
      asm volatile("s_waitcnt vmcnt(8)" ::: "memory");  // buf's 8 done; next 8 in flight
    } else {
      asm volatile("s_waitcnt vmcnt(0)" ::: "memory");  // last step: drain
    }
    __builtin_amdgcn_s_barrier();   // every wave's buf-loads have landed

    // S = Q K^T : 32q x 32k per wave; each K B-frag feeds 2 MFMAs (r=0,1)
    f32x4 s4[2][2];
    s4[0][0] = (f32x4){0.f, 0.f, 0.f, 0.f};
    s4[0][1] = s4[0][0]; s4[1][0] = s4[0][0]; s4[1][1] = s4[0][0];
#pragma unroll
    for (int s = 0; s < 8; s++) {
      bf16x8 b0 = *(const bf16x8*)(&Ksm[buf][s][l15][kx]);
      bf16x8 b1 = *(const bf16x8*)(&Ksm[buf][s][16 + l15][kx]);
      s4[0][0] = __builtin_amdgcn_mfma_f32_16x16x32_bf16(qf[0][s], b0, s4[0][0], 0, 0, 0);
      s4[0][1] = __builtin_amdgcn_mfma_f32_16x16x32_bf16(qf[0][s], b1, s4[0][1], 0, 0, 0);
      s4[1][0] = __builtin_amdgcn_mfma_f32_16x16x32_bf16(qf[1][s], b0, s4[1][0], 0, 0, 0);
      s4[1][1] = __builtin_amdgcn_mfma_f32_16x16x32_bf16(qf[1][s], b1, s4[1][1], 0, 0, 0);
    }

    // p = exp(50*tanh(v/50) - 50) = exp(-100/(e^{0.04v}+1)); max pinned at 50.
    const bool mk = (i == nst - 1);     // diagonal step for this sp
#pragma unroll
    for (int r = 0; r < 2; r++)
#pragma unroll
      for (int nt = 0; nt < 2; nt++) {
        const int key = t0 + nt * 16 + l15;
#pragma unroll
        for (int j = 0; j < 4; j++) {
          float v = s4[r][nt][j];
          float e = __expf(v * 0.04f);
          float p = __expf(-100.f * __builtin_amdgcn_rcpf(e + 1.f));
          if (mk && key > qbase + r * 16 + j) p = 0.f;
          s4[r][nt][j] = p;
          rs[r][j] += p;  // per-lane partial; cross-lane reduce at end
        }
      }

    // P: C-layout -> LDS -> A-layout (per-wave slab)
#pragma unroll
    for (int r = 0; r < 2; r++)
#pragma unroll
      for (int nt = 0; nt < 2; nt++)
#pragma unroll
        for (int j = 0; j < 4; j++)
          Pex[wave][r * 16 + quad * 4 + j][nt * 16 + l15] = (__bf16)s4[r][nt][j];

    bf16x8 pf0 = *(const bf16x8*)(&Pex[wave][l15][quad * 8]);
    bf16x8 pf1 = *(const bf16x8*)(&Pex[wave][16 + l15][quad * 8]);
#pragma unroll
    for (int d = 0; d < 16; d++) {
      bf16x8 vf = *(const bf16x8*)(&Vsm[buf][d * 16 + l15][kx]);
      o[0][d] = __builtin_amdgcn_mfma_f32_16x16x32_bf16(pf0, vf, o[0][d], 0, 0, 0);
      o[1][d] = __builtin_amdgcn_mfma_f32_16x16x32_bf16(pf1, vf, o[1][d], 0, 0, 0);
    }
  }

  // reduce row-sums over the 16 key-columns held across l15 lanes
#pragma unroll
  for (int off = 1; off < 16; off <<= 1)
#pragma unroll
    for (int r = 0; r < 2; r++)
#pragma unroll
      for (int j = 0; j < 4; j++) rs[r][j] += __shfl_xor(rs[r][j], off);

  _Float16* Os = Op + (size_t)sp * (2048 * 2048);
  float* Ls = Lp + sp * (2048 * 8);
#pragma unroll
  for (int r = 0; r < 2; r++) {
    float inv[4];
#pragma unroll
    for (int j = 0; j < 4; j++)
      inv[j] = rs[r][j] > 0.f ? 1.f / rs[r][j] : 0.f;
    const int trow = qt * 128 + wave * 32 + r * 16 + quad * 4;
#pragma unroll
    for (int d = 0; d < 16; d++) {
      const int col = h * 256 + d * 16 + l15;
#pragma unroll
      for (int j = 0; j < 4; j++)
        Os[(size_t)(trow + j) * 2048 + col] = (_Float16)(o[r][d][j] * inv[j]);
    }
    if (l15 == 0) {
#pragma unroll
      for (int j = 0; j < 4; j++) Ls[(trow + j) * 8 + h] = rs[r][j];
    }
  }
}

// ---------- merge: O = sum(l_i * Onorm_i) / sum(l_i) ----------
__global__ void merge_kernel(const _Float16* __restrict__ Op, const float* __restrict__ Lp,
                             __bf16* __restrict__ AO) {
  int f = (blockIdx.x * 256 + threadIdx.x) * 4;
  int q = f >> 11, col = f & 2047, h = col >> 8;
  float lsum = 0.f;
  float acc[4] = {0.f, 0.f, 0.f, 0.f};
#pragma unroll
  for (int s = 0; s < 4; s++) {
    float l = Lp[s * (2048 * 8) + q * 8 + h];
    lsum += l;
    f16x4 v = *(const f16x4*)(Op + (size_t)s * (2048 * 2048) + f);
#pragma unroll
    for (int j = 0; j < 4; j++) acc[j] += l * (float)v[j];
  }
  float inv = 1.f / lsum;
  bf16x4 o;
#pragma unroll
  for (int j = 0; j < 4; j++) o[j] = (__bf16)(acc[j] * inv);
  *(bf16x4*)(AO + f) = o;
}

extern "C" void kernel_launch(void* const* d_in, const int* in_sizes, int n_in,
                              void* d_out, int out_size, void* d_ws, size_t ws_size,
                              hipStream_t stream) {
  const float* hidden = (const float*)d_in[0];
  const float* cosb = (const float*)d_in[1];
  const float* sinb = (const float*)d_in[2];
  // d_in[3] attention_mask: causal, reproduced analytically
  const float* wq = (const float*)d_in[4];
  const float* wk = (const float*)d_in[5];
  const float* wv = (const float*)d_in[6];
  const float* wo = (const float*)d_in[7];
  const float* qw = (const float*)d_in[8];
  const float* kw = (const float*)d_in[9];
  const float* vw = (const float*)d_in[10];
  float* outp = (float*)d_out;

  char* p = (char*)d_ws;
  __bf16* Xb = (__bf16*)p;   p += (size_t)SEQL * HID * 2;       // 16 MB (dead after GEMMs)
  __bf16* WQT = (__bf16*)p;  p += (size_t)2048 * 2048 * 2;      // 8 MB  (dead after Q GEMM)
  __bf16* WKVT = (__bf16*)p; p += (size_t)2048 * 2048 * 2;      // 8 MB  (dead after KV GEMM)
  __bf16* WOT = (__bf16*)p;  p += (size_t)2048 * 2048 * 2;      // 8 MB
  __bf16* Qp = (__bf16*)p;   p += (size_t)2048 * 2048 * 2;      // 8 MB
  __bf16* KVp = (__bf16*)p;  p += (size_t)4096 * 2048 * 2;      // 16 MB
  __bf16* VT = (__bf16*)p;   p += (size_t)4 * 256 * 4096 * 2;   // 8 MB
  __bf16* AO = (__bf16*)p;   p += (size_t)2048 * 2048 * 2;      // 8 MB
  float* Lpart = (float*)p;  p += (size_t)4 * 2048 * 8 * 4;     // 256 KB (total ~80.3 MB)
  // fp16 normalized partial O (4 x 8 MB = 32 MB) overlays the dead
  // Xb(16)+WQT(8)+WKVT(8) regions (contiguous, end exactly at WOT).
  _Float16* Opart = (_Float16*)Xb;

  // 1) fused prep: X convert + all weight transposes (one launch)
  prep_kernel<<<11264, 256, 0, stream>>>(hidden, Xb, wq, wk, wv, wo, WQT, WKVT, WOT);

  // 2) fused Q + KV projections: 192 blocks of 256x256 (128 KV + 64 Q), 512 threads
  gemm256_kernel<0><<<192, 512, 0, stream>>>(Xb, WKVT, WQT, KVp, Qp);

  // 3) unified RMSNorm (+RoPE); V written back coalesced, then tiled transpose -> VT
  norm_all_kernel<<<12288, 256, 0, stream>>>(Qp, KVp, cosb, sinb, qw, kw, vw);
  vtrans_kernel<<<1024, 256, 0, stream>>>(KVp, VT);

  // 4) flash attention, interleaved KV-split x4 (L2-hot), fp16 normalized partials
  attn_kernel<<<512, 256, 0, stream>>>(Qp, KVp, VT, Opart, Lpart);
  merge_kernel<<<4096, 256, 0, stream>>>(Opart, Lpart, AO);

  // 5) output projection -> fp32 (128x128 tiles, 256 blocks, 2/CU)
  gemm_bt_kernel<4, true><<<dim3(16, 16), 256, 0, stream>>>(AO, WOT, outp, 2048, 2048, 2048);
}